// Round 8
// baseline (94.147 us; speedup 1.0000x reference)
//
#include <hip/hip_runtime.h>

#define NBINS 101
#define NB2 (2 * NBINS)    // 202 bins total (pos + neg)
#define NTHREADS 256
#define NCOPY 32           // histogram replicas, one per lane&31 (bank = copy)
#define CNT_SHIFT 22
#define QMAX 413695u       // (100<<12) | 4095 : clamps idx to <= 100

typedef _Float16 half8 __attribute__((ext_vector_type(8)));
typedef float floatx4 __attribute__((ext_vector_type(4)));

// ---------------------------------------------------------------------------
// R8: R7 confirmed the LDS-atomic model (205->89us from halving atomic ops).
// Profile now shows the harness's 268MB d_ws poison fill (~42us) is INSIDE
// dur_us -> fixed floor. Remaining controllables: (1) drop convert kernel,
// read f32 directly with in-register f16 cvt (R5 proved the pattern free);
// (2) one 64x64 triangle tile per WAVE (2080 jobs = 520 blocks x 4 waves,
// finer tail); (3) leaner binning: q = clamp(round((s+1)*204800)) ->
// idx=q>>12, word=(1<<22)|(q&4095), single ds_add_u32, ~9 VALU/pair.
// Packed-overflow proof: 8 threads share a (bin,copy) => <=512 adds/block
// => count <= 512 < 2^10, sum(frac) <= 512*4095 < 2^22.
// ---------------------------------------------------------------------------

__device__ inline half8 ld_cvt8(const float* __restrict__ p) {
    float4 f0 = *(const float4*)p;
    float4 f1 = *(const float4*)(p + 4);
    half8 h;
    h[0] = (_Float16)f0.x; h[1] = (_Float16)f0.y;
    h[2] = (_Float16)f0.z; h[3] = (_Float16)f0.w;
    h[4] = (_Float16)f1.x; h[5] = (_Float16)f1.y;
    h[6] = (_Float16)f1.z; h[7] = (_Float16)f1.w;
    return h;
}

__global__ __launch_bounds__(NTHREADS, 4)
void hist_pairs_kernel(const float* __restrict__ feats,
                       const int* __restrict__ classes,
                       float* __restrict__ partials,  // [nblocks][NB2]
                       int ntiles, int njobs) {
    __shared__ unsigned lhist[NB2][NCOPY];   // packed count|frac, 25.9 KB
    __shared__ float Fbuf[NB2];
    __shared__ __align__(16) int cls[4][2][64];  // [wave][A/B][row]

    const int tid = threadIdx.x;
    const int wave = tid >> 6;
    const int lane = tid & 63;

    // zero local histograms
    for (int t = tid; t < NB2 * NCOPY; t += NTHREADS)
        (&lhist[0][0])[t] = 0u;

    // one 64x64 upper-triangular tile per wave
    const int job = blockIdx.x * 4 + wave;
    int ti = 0, tj = 0;
    if (job < njobs) {
        int rem = job;
        while (rem >= ntiles - ti) { rem -= ntiles - ti; ++ti; }
        tj = ti + rem;
        cls[wave][0][lane] = classes[ti * 64 + lane];
        cls[wave][1][lane] = classes[tj * 64 + lane];
    }
    __syncthreads();

    if (job < njobs) {
        const int i0 = ti * 64, j0 = tj * 64;
        const int lr = lane & 15;
        const int quad = lane >> 4;

        const float* Ab = feats + (size_t)(i0 + lr) * 128 + quad * 8;
        const float* Bb = feats + (size_t)(j0 + lr) * 128 + quad * 8;

        floatx4 acc[4][4] = {};
        #pragma unroll
        for (int ks = 0; ks < 128; ks += 32) {
            half8 af[4], bf[4];
            #pragma unroll
            for (int mi = 0; mi < 4; ++mi)
                af[mi] = ld_cvt8(Ab + (size_t)mi * 16 * 128 + ks);
            #pragma unroll
            for (int ni = 0; ni < 4; ++ni)
                bf[ni] = ld_cvt8(Bb + (size_t)ni * 16 * 128 + ks);
            #pragma unroll
            for (int mi = 0; mi < 4; ++mi)
                #pragma unroll
                for (int ni = 0; ni < 4; ++ni)
                    acc[mi][ni] = __builtin_amdgcn_mfma_f32_16x16x32_f16(
                        af[mi], bf[ni], acc[mi][ni], 0, 0, 0);
        }

        // classes for this lane's C fragment rows/cols
        int cA[4][4], cB[4];
        #pragma unroll
        for (int mi = 0; mi < 4; ++mi) {
            int4 c4 = *(const int4*)&cls[wave][0][mi * 16 + quad * 4];
            cA[mi][0] = c4.x; cA[mi][1] = c4.y;
            cA[mi][2] = c4.z; cA[mi][3] = c4.w;
        }
        #pragma unroll
        for (int ni = 0; ni < 4; ++ni) cB[ni] = cls[wave][1][ni * 16 + lr];

        // binning: one packed ds_add_u32 per pair.
        // C-layout: col = lane&15, row = quad*4 + reg.
        const int copy = lane & (NCOPY - 1);
        unsigned* hb = &lhist[0][0];
        const bool diag = (ti == tj);
        #pragma unroll
        for (int mi = 0; mi < 4; ++mi) {
            #pragma unroll
            for (int ni = 0; ni < 4; ++ni) {
                #pragma unroll
                for (int r = 0; r < 4; ++r) {
                    const int li = mi * 16 + quad * 4 + r;
                    const int lj = ni * 16 + lr;
                    if (diag && li >= lj) continue;  // strict upper triangle
                    float s = acc[mi][ni][r];
                    // q = round((s+1) * 50 * 4096), saturating at 0
                    float qf = fmaf(s, 204800.0f, 204800.5f);
                    qf = fmaxf(qf, 0.0f);
                    unsigned q = (unsigned)qf;
                    q = q > QMAX ? QMAX : q;
                    unsigned idx = q >> 12;
                    unsigned word = (q & 4095u) | (1u << CNT_SHIFT);
                    unsigned hoff = (cA[mi][r] == cB[ni]) ? 0u : (unsigned)NBINS;
                    atomicAdd(&hb[(hoff + idx) * NCOPY + copy], word);
                }
            }
        }
    }
    __syncthreads();

    // per-bin unpack: C = sum(w>>22), F = sum(w&mask)/4096, then telescope:
    // h[t] = C[t] - (t<hi)F[t] + (t>lo)F[t-1]  per 101-bin segment
    const int t = tid;
    float myC = 0.0f, myF = 0.0f;
    if (t < NB2) {
        unsigned Cs = 0, Fq = 0;
        #pragma unroll
        for (int c = 0; c < NCOPY; ++c) {
            unsigned w = lhist[t][(c + t) & (NCOPY - 1)];
            Cs += w >> CNT_SHIFT;
            Fq += w & ((1u << CNT_SHIFT) - 1);   // <= 32*2^21 = 2^26, safe
        }
        myC = (float)Cs;
        myF = (float)Fq * (1.0f / 4096.0f);
        Fbuf[t] = myF;
    }
    __syncthreads();
    if (t < NB2) {
        const int lo = (t < NBINS) ? 0 : NBINS;
        const int hi = lo + NBINS - 1;
        float h = myC;
        if (t < hi) h -= myF;
        if (t > lo) h += Fbuf[t - 1];
        partials[(size_t)blockIdx.x * NB2 + t] = h;
    }
}

// ---------------------------------------------------------------------------
// Sum partial rows (coalesced, 5-way row split), then fp64 finalize:
// normalize, inclusive cumsum of pos, dot with neg.
// ---------------------------------------------------------------------------
__global__ __launch_bounds__(1024)
void reduce_finalize_kernel(const float* __restrict__ partials,
                            float* __restrict__ out, int nrows) {
    __shared__ float acc[5][NB2];
    __shared__ float h[NB2];
    const int t = threadIdx.x;
    const int g = t / NB2;          // group 0..4 (t >= 1010 idle)
    const int bin = t - g * NB2;
    if (g < 5) {
        float s = 0.0f;
        #pragma unroll 4
        for (int r = g; r < nrows; r += 5)
            s += partials[(size_t)r * NB2 + bin];
        acc[g][bin] = s;
    }
    __syncthreads();
    if (t < NB2)
        h[t] = acc[0][t] + acc[1][t] + acc[2][t] + acc[3][t] + acc[4][t];
    __syncthreads();
    if (t == 0) {
        double sp = 0.0, sn = 0.0;
        for (int k = 0; k < NBINS; ++k) { sp += h[k]; sn += h[NBINS + k]; }
        double isp = 1.0 / sp, isn = 1.0 / sn;
        double cdf = 0.0, res = 0.0;
        for (int k = 0; k < NBINS; ++k) {
            cdf += (double)h[k] * isp;                 // inclusive cumsum of pos
            res += (double)h[NBINS + k] * isn * cdf;   // dot with neg
        }
        out[0] = (float)res;
    }
}

extern "C" void kernel_launch(void* const* d_in, const int* in_sizes, int n_in,
                              void* d_out, int out_size, void* d_ws, size_t ws_size,
                              hipStream_t stream) {
    const float* feats   = (const float*)d_in[0];
    const int*   classes = (const int*)d_in[1];
    float* out      = (float*)d_out;
    float* partials = (float*)d_ws;            // [nblocks][NB2], plain stores

    int N = in_sizes[1];                       // 4096
    int ntiles = N / 64;                       // 64
    int njobs = ntiles * (ntiles + 1) / 2;     // 2080 wave-jobs
    int nblocks = (njobs + 3) / 4;             // 520 blocks, 4 jobs each

    hist_pairs_kernel<<<nblocks, NTHREADS, 0, stream>>>(feats, classes,
                                                        partials, ntiles, njobs);
    reduce_finalize_kernel<<<1, 1024, 0, stream>>>(partials, out, nblocks);
}

// Round 9
// 85.989 us; speedup vs baseline: 1.0949x; 1.0949x over previous
//
#include <hip/hip_runtime.h>

#define NBINS 101
#define NB2 (2 * NBINS)    // 202 bins total (pos + neg)
#define NTHREADS 256
#define NCOPY 32           // histogram replicas, one per lane&31 (bank = copy)
#define CNT_SHIFT 22
#define QMAX 413695u       // (100<<12) | 4095 : clamps idx to <= 100
#define FSCALE 452.5483399593904f   // sqrt(50 * 4096): folds (s+1)*204800 into MFMA

typedef _Float16 half8 __attribute__((ext_vector_type(8)));
typedef float floatx4 __attribute__((ext_vector_type(4)));

// ---------------------------------------------------------------------------
// R9: recombination of measured-best pieces. R8 regression isolated to f32
// direct loads + in-loop cvt (R5's "free" claim was masked by the old atomic
// floor). Restore the f16 workspace (convert kernel), and fold the binning
// affine into it: wsF = x * sqrt(204800), acc init = 204800.5f, so MFMA
// emits q-space directly and per-pair binning is ~9 VALU + 1 ds_add_u32.
// Per-wave 64x64 triangle jobs (2080 = 520 blocks x 4 waves) for a fine
// tail. Packed overflow-proof: <=512 adds per (bin,copy) per block.
// ---------------------------------------------------------------------------

__global__ __launch_bounds__(NTHREADS)
void convert_kernel(const float* __restrict__ feats,
                    const int* __restrict__ classes,
                    _Float16* __restrict__ wsF,
                    unsigned char* __restrict__ wsC,
                    int ngroups,   // N*D/8 groups of 8 floats
                    int n) {       // N (classes)
    int t = blockIdx.x * NTHREADS + threadIdx.x;
    if (t < ngroups) {
        const float4* p = (const float4*)feats + (size_t)t * 2;
        float4 f0 = p[0];
        float4 f1 = p[1];
        half8 h;
        h[0] = (_Float16)(f0.x * FSCALE); h[1] = (_Float16)(f0.y * FSCALE);
        h[2] = (_Float16)(f0.z * FSCALE); h[3] = (_Float16)(f0.w * FSCALE);
        h[4] = (_Float16)(f1.x * FSCALE); h[5] = (_Float16)(f1.y * FSCALE);
        h[6] = (_Float16)(f1.z * FSCALE); h[7] = (_Float16)(f1.w * FSCALE);
        *(half8*)(wsF + (size_t)t * 8) = h;
    }
    if (t < n) wsC[t] = (unsigned char)classes[t];
}

// ---------------------------------------------------------------------------
// One 64x64 upper-triangular tile per wave; half8 fragment loads from the
// scaled f16 workspace; acc arrives in q-space (bias pre-added); one
// ds_add_u32 per pair; per-block unpack + telescope -> partials row.
// ---------------------------------------------------------------------------
__global__ __launch_bounds__(NTHREADS, 4)
void hist_pairs_kernel(const _Float16* __restrict__ feats16,
                       const unsigned char* __restrict__ cls8,
                       float* __restrict__ partials,  // [nblocks][NB2]
                       int ntiles, int njobs) {
    __shared__ unsigned lhist[NB2][NCOPY];   // packed count|frac, 25.9 KB
    __shared__ float Fbuf[NB2];
    __shared__ __align__(16) int cls[4][2][64];  // [wave][A/B][row]

    const int tid = threadIdx.x;
    const int wave = tid >> 6;
    const int lane = tid & 63;

    // zero local histograms (uint4 stores: 1616 x 16B / 256 thr)
    {
        uint4* z = (uint4*)&lhist[0][0];
        uint4 zero = {0u, 0u, 0u, 0u};
        for (int t = tid; t < NB2 * NCOPY / 4; t += NTHREADS) z[t] = zero;
    }

    // one 64x64 upper-triangular tile per wave
    const int job = blockIdx.x * 4 + wave;
    int ti = 0, tj = 0;
    if (job < njobs) {
        int rem = job;
        while (rem >= ntiles - ti) { rem -= ntiles - ti; ++ti; }
        tj = ti + rem;
        cls[wave][0][lane] = cls8[ti * 64 + lane];
        cls[wave][1][lane] = cls8[tj * 64 + lane];
    }
    __syncthreads();

    if (job < njobs) {
        const int i0 = ti * 64, j0 = tj * 64;
        const int lr = lane & 15;
        const int quad = lane >> 4;

        const _Float16* Ab = feats16 + (size_t)(i0 + lr) * 128 + quad * 8;
        const _Float16* Bb = feats16 + (size_t)(j0 + lr) * 128 + quad * 8;

        // acc initialized to the binning bias: (s+1)*204800 + 0.5 rounding
        floatx4 acc[4][4];
        #pragma unroll
        for (int mi = 0; mi < 4; ++mi)
            #pragma unroll
            for (int ni = 0; ni < 4; ++ni) {
                acc[mi][ni][0] = 204800.5f; acc[mi][ni][1] = 204800.5f;
                acc[mi][ni][2] = 204800.5f; acc[mi][ni][3] = 204800.5f;
            }

        #pragma unroll
        for (int ks = 0; ks < 128; ks += 32) {
            half8 af[4], bf[4];
            #pragma unroll
            for (int mi = 0; mi < 4; ++mi)
                af[mi] = *(const half8*)(Ab + (size_t)mi * 16 * 128 + ks);
            #pragma unroll
            for (int ni = 0; ni < 4; ++ni)
                bf[ni] = *(const half8*)(Bb + (size_t)ni * 16 * 128 + ks);
            #pragma unroll
            for (int mi = 0; mi < 4; ++mi)
                #pragma unroll
                for (int ni = 0; ni < 4; ++ni)
                    acc[mi][ni] = __builtin_amdgcn_mfma_f32_16x16x32_f16(
                        af[mi], bf[ni], acc[mi][ni], 0, 0, 0);
        }

        // classes for this lane's C fragment rows/cols
        int cA[4][4], cB[4];
        #pragma unroll
        for (int mi = 0; mi < 4; ++mi) {
            int4 c4 = *(const int4*)&cls[wave][0][mi * 16 + quad * 4];
            cA[mi][0] = c4.x; cA[mi][1] = c4.y;
            cA[mi][2] = c4.z; cA[mi][3] = c4.w;
        }
        #pragma unroll
        for (int ni = 0; ni < 4; ++ni) cB[ni] = cls[wave][1][ni * 16 + lr];

        // binning: acc already equals q + tiny fp noise. One ds_add_u32/pair.
        const int copy = lane & (NCOPY - 1);
        unsigned* hb = &lhist[0][0] + copy;
        const bool diag = (ti == tj);
        #pragma unroll
        for (int mi = 0; mi < 4; ++mi) {
            #pragma unroll
            for (int ni = 0; ni < 4; ++ni) {
                #pragma unroll
                for (int r = 0; r < 4; ++r) {
                    const int li = mi * 16 + quad * 4 + r;
                    const int lj = ni * 16 + lr;
                    if (diag && li >= lj) continue;  // strict upper triangle
                    float qf = fmaxf(acc[mi][ni][r], 0.0f);
                    unsigned q = (unsigned)qf;
                    q = q > QMAX ? QMAX : q;
                    unsigned idx = q >> 12;
                    unsigned word = (q & 4095u) | (1u << CNT_SHIFT);
                    unsigned hoff = (cA[mi][r] == cB[ni]) ? 0u : (unsigned)NBINS;
                    atomicAdd(hb + (hoff + idx) * NCOPY, word);
                }
            }
        }
    }
    __syncthreads();

    // per-bin unpack: C = sum(w>>22), F = sum(w&mask)/4096, then telescope:
    // h[t] = C[t] - (t<hi)F[t] + (t>lo)F[t-1]  per 101-bin segment
    const int t = tid;
    float myC = 0.0f, myF = 0.0f;
    if (t < NB2) {
        unsigned Cs = 0, Fq = 0;
        #pragma unroll
        for (int c = 0; c < NCOPY; ++c) {
            unsigned w = lhist[t][(c + t) & (NCOPY - 1)];
            Cs += w >> CNT_SHIFT;
            Fq += w & ((1u << CNT_SHIFT) - 1);   // <= 32*2^21 = 2^26, safe
        }
        myC = (float)Cs;
        myF = (float)Fq * (1.0f / 4096.0f);
        Fbuf[t] = myF;
    }
    __syncthreads();
    if (t < NB2) {
        const int lo = (t < NBINS) ? 0 : NBINS;
        const int hi = lo + NBINS - 1;
        float h = myC;
        if (t < hi) h -= myF;
        if (t > lo) h += Fbuf[t - 1];
        partials[(size_t)blockIdx.x * NB2 + t] = h;
    }
}

// ---------------------------------------------------------------------------
// Sum partial rows (coalesced, 5-way row split), then fp64 finalize:
// normalize, inclusive cumsum of pos, dot with neg.
// ---------------------------------------------------------------------------
__global__ __launch_bounds__(1024)
void reduce_finalize_kernel(const float* __restrict__ partials,
                            float* __restrict__ out, int nrows) {
    __shared__ float acc[5][NB2];
    __shared__ float h[NB2];
    const int t = threadIdx.x;
    const int g = t / NB2;          // group 0..4 (t >= 1010 idle)
    const int bin = t - g * NB2;
    if (g < 5) {
        float s = 0.0f;
        #pragma unroll 4
        for (int r = g; r < nrows; r += 5)
            s += partials[(size_t)r * NB2 + bin];
        acc[g][bin] = s;
    }
    __syncthreads();
    if (t < NB2)
        h[t] = acc[0][t] + acc[1][t] + acc[2][t] + acc[3][t] + acc[4][t];
    __syncthreads();
    if (t == 0) {
        double sp = 0.0, sn = 0.0;
        for (int k = 0; k < NBINS; ++k) { sp += h[k]; sn += h[NBINS + k]; }
        double isp = 1.0 / sp, isn = 1.0 / sn;
        double cdf = 0.0, res = 0.0;
        for (int k = 0; k < NBINS; ++k) {
            cdf += (double)h[k] * isp;                 // inclusive cumsum of pos
            res += (double)h[NBINS + k] * isn * cdf;   // dot with neg
        }
        out[0] = (float)res;
    }
}

extern "C" void kernel_launch(void* const* d_in, const int* in_sizes, int n_in,
                              void* d_out, int out_size, void* d_ws, size_t ws_size,
                              hipStream_t stream) {
    const float* feats   = (const float*)d_in[0];
    const int*   classes = (const int*)d_in[1];
    float* out = (float*)d_out;

    int N = in_sizes[1];                       // 4096
    int D = in_sizes[0] / N;                   // 128
    int ntiles = N / 64;                       // 64
    int njobs = ntiles * (ntiles + 1) / 2;     // 2080 wave-jobs
    int nblocks = (njobs + 3) / 4;             // 520 blocks, 4 jobs each

    // workspace layout: f16 scaled feats | u8 classes | fp32 partials
    _Float16* wsF = (_Float16*)d_ws;
    unsigned char* wsC = (unsigned char*)(wsF + (size_t)N * D);
    float* partials = (float*)(wsC + ((N + 15) & ~15));

    int ngroups = N * D / 8;                   // 65536 groups of 8 floats
    int cblocks = (ngroups + NTHREADS - 1) / NTHREADS;
    convert_kernel<<<cblocks, NTHREADS, 0, stream>>>(feats, classes, wsF, wsC,
                                                     ngroups, N);
    hist_pairs_kernel<<<nblocks, NTHREADS, 0, stream>>>(wsF, wsC, partials,
                                                        ntiles, njobs);
    reduce_finalize_kernel<<<1, 1024, 0, stream>>>(partials, out, nblocks);
}